// Round 9
// baseline (219.171 us; speedup 1.0000x reference)
//
#include <hip/hip_runtime.h>
#include <hip/hip_bf16.h>

typedef __attribute__((ext_vector_type(8))) short s8v;    // 8 bf16
typedef __attribute__((ext_vector_type(4))) short s4v;    // 4 bf16
typedef __attribute__((ext_vector_type(4))) float f4v;    // 4 fp32

__device__ __forceinline__ void g2lds16(const void* g, void* l) {
  __builtin_amdgcn_global_load_lds(
      (__attribute__((address_space(1))) void*)(g),
      (__attribute__((address_space(3))) void*)(l), 16, 0, 0);
}

__device__ __forceinline__ short f2bf(float f) {
  __hip_bfloat16 h = __float2bfloat16(f);
  return *reinterpret_cast<short*>(&h);
}

// ---------------- K0: fused x->bf16 cvt  +  W transpose->bf16 ----------------
__global__ void k_prep(const float* __restrict__ x, const float* __restrict__ W,
                       __hip_bfloat16* __restrict__ xb, __hip_bfloat16* __restrict__ Wt) {
  int bx = blockIdx.x;
  if (bx < 4096) {
    int i = (bx * 256 + threadIdx.x) * 4;
    float4 v = *(const float4*)(x + i);
    __hip_bfloat16 o[4] = {__float2bfloat16(v.x), __float2bfloat16(v.y),
                           __float2bfloat16(v.z), __float2bfloat16(v.w)};
    *(uint2*)(xb + i) = *(const uint2*)(o);
  } else {
    __shared__ float tile[32][33];
    int r = bx - 4096;            // 0..3071 = 32 x 96
    int rt = r / 96;              // over 1024/32
    int ct = r - rt * 96;         // over 3072/32
    int c0 = ct * 32, r0 = rt * 32;
    int tr = threadIdx.x >> 5, tc = threadIdx.x & 31;
#pragma unroll
    for (int i = 0; i < 32; i += 8)
      tile[tr + i][tc] = W[(size_t)(r0 + tr + i) * 3072 + c0 + tc];
    __syncthreads();
#pragma unroll
    for (int i = 0; i < 32; i += 8)
      Wt[(size_t)(c0 + tr + i) * 1024 + r0 + tc] = __float2bfloat16(tile[tc][tr + i]);
  }
}

// ---------------- K1: GEMM + fused QKV scatter epilogue ----------------
// (unchanged known-good: 128^2 tile, BK=32, 4 waves, 768 blocks, ~57.5us.
//  Attention scale 0.125*log2e folded into Q at the epilogue.)
__global__ __launch_bounds__(256) void k_gemm(const __hip_bfloat16* __restrict__ A,
                                              const __hip_bfloat16* __restrict__ Bt,
                                              const float* __restrict__ bias,
                                              __hip_bfloat16* __restrict__ Q,
                                              __hip_bfloat16* __restrict__ K,
                                              __hip_bfloat16* __restrict__ Vt) {
  __shared__ __align__(16) __hip_bfloat16 As[2][128 * 32];
  __shared__ __align__(16) __hip_bfloat16 Bs[2][128 * 32];
  const int tid = threadIdx.x;
  const int lane = tid & 63, wave = tid >> 6;
  const int m0 = blockIdx.y * 128, n0 = blockIdx.x * 128;
  const int wm = (wave & 1) * 64, wn = (wave >> 1) * 64;
  const int lrow = lane & 15;
  const int quad = lane >> 4;

  f4v acc[4][4] = {};

  auto stage = [&](int k0, int kb) {
#pragma unroll
    for (int c = 0; c < 2; ++c) {
      int e = c * 2048 + tid * 8;             // element idx in 128x32 tile
      int row = e >> 5;
      int slot = (e & 31) >> 3;               // 0..3 (8-elem slots)
      int src = k0 + ((slot ^ ((row >> 1) & 3)) << 3);
      g2lds16(A + (size_t)(m0 + row) * 1024 + src, &As[kb][e]);
      g2lds16(Bt + (size_t)(n0 + row) * 1024 + src, &Bs[kb][e]);
    }
  };

  const int swz = (quad ^ ((lrow >> 1) & 3)) * 8;  // swizzled k-slot for frag reads

  stage(0, 0);
  for (int it = 0; it < 32; ++it) {
    __syncthreads();                    // drains stage(it) (issued one iter ago)
    if (it < 31) stage((it + 1) * 32, (it + 1) & 1);
    const __hip_bfloat16* Ab = As[it & 1];
    const __hip_bfloat16* Bb = Bs[it & 1];
    s8v af[4], bfr[4];
#pragma unroll
    for (int mi = 0; mi < 4; ++mi) af[mi] = *(const s8v*)(Ab + (wm + mi * 16 + lrow) * 32 + swz);
#pragma unroll
    for (int ni = 0; ni < 4; ++ni) bfr[ni] = *(const s8v*)(Bb + (wn + ni * 16 + lrow) * 32 + swz);
#pragma unroll
    for (int mi = 0; mi < 4; ++mi)
#pragma unroll
      for (int ni = 0; ni < 4; ++ni)
        acc[mi][ni] = __builtin_amdgcn_mfma_f32_16x16x32_bf16(af[mi], bfr[ni], acc[mi][ni], 0, 0, 0);
  }

  // epilogue: per-row destination decode, d-packed 8B stores for Q/K
  const int cw = n0 + wn;            // multiple of 64 -> c10 wave-uniform
  const int c10 = cw >> 10;          // 0..2
  const int d0 = (cw & 1023) >> 4;   // multiple of 4
  const int h = lrow;
  float bv[4];
#pragma unroll
  for (int ni = 0; ni < 4; ++ni) bv[ni] = bias[cw + ni * 16 + lrow];

#pragma unroll
  for (int mi = 0; mi < 4; ++mi) {
    int rbase = m0 + wm + mi * 16 + quad * 4;
#pragma unroll
    for (int reg = 0; reg < 4; ++reg) {
      int rr = rbase + reg;
      int u = 3 * rr + c10;
      int s = u >> 12;
      int b = (u >> 11) & 1;
      int t = u & 2047;
      if (s < 2) {
        __hip_bfloat16* dst = (s == 0) ? Q : K;
        // Q carries the attention scale: 0.125 * log2(e)
        const float qs = (s == 0) ? 0.18033688011112042f : 1.0f;
        s4v pk;
#pragma unroll
        for (int ni = 0; ni < 4; ++ni) pk[ni] = f2bf((acc[mi][ni][reg] + bv[ni]) * qs);
        *(s4v*)(dst + ((size_t)(b * 16 + h) * 2048 + t) * 64 + d0) = pk;
      } else {
#pragma unroll
        for (int ni = 0; ni < 4; ++ni)
          Vt[((size_t)(b * 16 + h) * 64 + d0 + ni) * 2048 + t] =
              __float2bfloat16(acc[mi][ni][reg] + bv[ni]);
      }
    }
  }
}

// ---------------- K2: causal flash attention, balanced 2 Q-tiles/block -----
// 512 blocks x 4 waves, 2 blocks/CU. Block k (k=0..15) of each bh owns the
// COMPLEMENTARY pair qA=k, qB=31-k and sweeps KV tiles 0..qB once. Chain A
// is computed only while j<=qA (block-uniform branch, skipped not masked).
// Work/block = 2(k+1) + (31-2k) = 33 units for EVERY k -> zero imbalance,
// zero tail (round-8's 64-unit critical block was the regression). On doubled
// tiles the K/V ds_reads are shared by both chains and the two softmax chains
// give 2-way ILP.
__global__ __launch_bounds__(256, 2) void k_attn(const __hip_bfloat16* __restrict__ Q,
                                                 const __hip_bfloat16* __restrict__ K,
                                                 const __hip_bfloat16* __restrict__ Vt,
                                                 float* __restrict__ out) {
  __shared__ __align__(16) char lds[2][16384];  // per buf: K tile 8KB | V tile 8KB

  const int tid = threadIdx.x;
  const int lane = tid & 63, w = tid >> 6;
  const int l = lane & 15, q = lane >> 4, lx = l & 7;

  const int bid = blockIdx.x;           // 512 blocks
  const int xcd = bid & 7;
  const int idx = bid >> 3;             // 0..63
  const int bh = xcd + 8 * (idx & 3);   // 4 bh per XCD -> 2MB K+V in its L2
  const int kk = idx >> 2;              // 0..15
  const int qA = kk, qB = 31 - kk;      // complementary pair, 33 units/block

  const char* Kb = (const char*)(K + (size_t)bh * 131072);
  const char* Vb = (const char*)(Vt + (size_t)bh * 131072);
  const __hip_bfloat16* QpA = Q + (size_t)bh * 131072 + (size_t)qA * 4096;
  const __hip_bfloat16* QpB = Q + (size_t)bh * 131072 + (size_t)qB * 4096;

  // Q fragments (load once): B[n=t][k], t = q?*64 + w*16 + l
  s8v QfA[2], QfB[2];
#pragma unroll
  for (int kh = 0; kh < 2; ++kh) {
    QfA[kh] = *(const s8v*)(QpA + (size_t)(w * 16 + l) * 64 + kh * 32 + q * 8);
    QfB[kh] = *(const s8v*)(QpB + (size_t)(w * 16 + l) * 64 + kh * 32 + q * 8);
  }

  f4v OA[4] = {}, OB[4] = {};
  float mA = -INFINITY, lsA = 0.f;
  float mB = -INFINITY, lsB = 0.f;
  const int tgA = qA * 64 + w * 16 + l;         // lane's global Q row, chain A
  const int tgB = qB * 64 + w * 16 + l;         // chain B

  auto stage = [&](int j, char* buf) {
#pragma unroll
    for (int c = 0; c < 4; ++c) {
      int chunk = w * 4 + c;            // 0..15
      int ls = chunk * 64 + lane;       // 16B-slot index
      if (chunk < 8) {                  // K tile: LDS[row][kb] = K[row][kb ^ (row&7)]
        int row = ls >> 3, kb = ls & 7;
        g2lds16(Kb + (size_t)j * 8192 + row * 128 + ((kb ^ (row & 7)) << 4),
                buf + ls * 16);
      } else {                          // V tile: LDS[d][kb] = V^T[d][kb ^ (d&7)]
        int ls2 = ls - 512;
        int d = ls2 >> 3, kb = ls2 & 7;
        g2lds16(Vb + (size_t)d * 4096 + (size_t)j * 128 + ((kb ^ (d & 7)) << 4),
                buf + 8192 + ls2 * 16);
      }
    }
  };

  stage(0, lds[0]);
  __syncthreads();

  for (int j = 0; j <= qB; ++j) {
    const char* Kl = lds[j & 1];
    const char* Vl = Kl + 8192;
    if (j < qB) stage(j + 1, lds[(j + 1) & 1]);
    const bool actA = (j <= qA);        // block-uniform

    // S^T: A-operand = K rows (shared ds_reads), B = Qf{A,B}
    f4v SA[4], SB[4];
#pragma unroll
    for (int nt = 0; nt < 4; ++nt) {
      const char* rowp = Kl + (nt * 16 + l) * 128;
      s8v k0 = *(const s8v*)(rowp + ((q ^ lx) << 4));
      s8v k1 = *(const s8v*)(rowp + (((4 + q) ^ lx) << 4));
      f4v zB = {0.f, 0.f, 0.f, 0.f};
      zB = __builtin_amdgcn_mfma_f32_16x16x32_bf16(k0, QfB[0], zB, 0, 0, 0);
      zB = __builtin_amdgcn_mfma_f32_16x16x32_bf16(k1, QfB[1], zB, 0, 0, 0);
      SB[nt] = zB;
      if (actA) {
        f4v zA = {0.f, 0.f, 0.f, 0.f};
        zA = __builtin_amdgcn_mfma_f32_16x16x32_bf16(k0, QfA[0], zA, 0, 0, 0);
        zA = __builtin_amdgcn_mfma_f32_16x16x32_bf16(k1, QfA[1], zA, 0, 0, 0);
        SA[nt] = zA;
      }
    }

    // causal masks (block-uniform rare branches)
    if (j == qB) {
#pragma unroll
      for (int nt = 0; nt < 4; ++nt)
#pragma unroll
        for (int r = 0; r < 4; ++r)
          if (j * 64 + nt * 16 + q * 4 + r > tgB) SB[nt][r] = -1e30f;
    }

    // chain B softmax (always active)
    float mxB = SB[0][0];
#pragma unroll
    for (int nt = 0; nt < 4; ++nt)
#pragma unroll
      for (int r = 0; r < 4; ++r) mxB = fmaxf(mxB, SB[nt][r]);
    mxB = fmaxf(mxB, __shfl_xor(mxB, 16));
    mxB = fmaxf(mxB, __shfl_xor(mxB, 32));
    if (!__all(mxB - mB <= 8.f)) {
      float mn = fmaxf(mB, mxB);
      float alpha = exp2f(mB - mn);
      mB = mn;
      lsB *= alpha;
#pragma unroll
      for (int dt = 0; dt < 4; ++dt) OB[dt] *= alpha;
    }
    float rsB = 0.f;
    s4v PfB[4];
    s4v PfA[4];
    float rsA = 0.f;

    if (actA) {
      // chain A: mask at its last tile, then softmax (interleaved with B's
      // exp pass below for ILP via independent chains)
      if (j == qA) {
#pragma unroll
        for (int nt = 0; nt < 4; ++nt)
#pragma unroll
          for (int r = 0; r < 4; ++r)
            if (j * 64 + nt * 16 + q * 4 + r > tgA) SA[nt][r] = -1e30f;
      }
      float mxA = SA[0][0];
#pragma unroll
      for (int nt = 0; nt < 4; ++nt)
#pragma unroll
        for (int r = 0; r < 4; ++r) mxA = fmaxf(mxA, SA[nt][r]);
      mxA = fmaxf(mxA, __shfl_xor(mxA, 16));
      mxA = fmaxf(mxA, __shfl_xor(mxA, 32));
      if (!__all(mxA - mA <= 8.f)) {
        float mn = fmaxf(mA, mxA);
        float alpha = exp2f(mA - mn);
        mA = mn;
        lsA *= alpha;
#pragma unroll
        for (int dt = 0; dt < 4; ++dt) OA[dt] *= alpha;
      }
#pragma unroll
      for (int nt = 0; nt < 4; ++nt)
#pragma unroll
        for (int r = 0; r < 4; ++r) {
          float eA = exp2f(SA[nt][r] - mA);
          float eB = exp2f(SB[nt][r] - mB);
          rsA += eA;
          rsB += eB;
          PfA[nt][r] = f2bf(eA);
          PfB[nt][r] = f2bf(eB);
        }
      rsA += __shfl_xor(rsA, 16);
      rsB += __shfl_xor(rsB, 16);
      rsA += __shfl_xor(rsA, 32);
      rsB += __shfl_xor(rsB, 32);
      lsA += rsA;
      lsB += rsB;
    } else {
#pragma unroll
      for (int nt = 0; nt < 4; ++nt)
#pragma unroll
        for (int r = 0; r < 4; ++r) {
          float eB = exp2f(SB[nt][r] - mB);
          rsB += eB;
          PfB[nt][r] = f2bf(eB);
        }
      rsB += __shfl_xor(rsB, 16);
      rsB += __shfl_xor(rsB, 32);
      lsB += rsB;
    }

    // PV: V^T ds_reads shared between chains
#pragma unroll
    for (int sc = 0; sc < 4; ++sc) {
      int so = ((sc * 2 + (q >> 1)) ^ lx) * 16 + (q & 1) * 8;
#pragma unroll
      for (int dt = 0; dt < 4; ++dt) {
        s4v vv = *(const s4v*)(Vl + (dt * 16 + l) * 128 + so);
        OB[dt] = __builtin_amdgcn_mfma_f32_16x16x16bf16_1k(vv, PfB[sc], OB[dt], 0, 0, 0);
        if (actA)
          OA[dt] = __builtin_amdgcn_mfma_f32_16x16x16bf16_1k(vv, PfA[sc], OA[dt], 0, 0, 0);
      }
    }
    __syncthreads();  // staging of j+1 drained; all waves done with buf (j&1)
  }

  // epilogue: two rows per lane -> float4 stores
  float invA = 1.f / lsA, invB = 1.f / lsB;
  int b = bh >> 4, h = bh & 15;
  float* obA = out + ((size_t)b * 2048 + tgA) * 1024 + h * 64;
  float* obB = out + ((size_t)b * 2048 + tgB) * 1024 + h * 64;
#pragma unroll
  for (int dt = 0; dt < 4; ++dt) {
    f4v vA = OA[dt] * invA;
    f4v vB = OB[dt] * invB;
    *(f4v*)(obA + dt * 16 + q * 4) = vA;
    *(f4v*)(obB + dt * 16 + q * 4) = vB;
  }
}

extern "C" void kernel_launch(void* const* d_in, const int* in_sizes, int n_in,
                              void* d_out, int out_size, void* d_ws, size_t ws_size,
                              hipStream_t stream) {
  const float* x = (const float*)d_in[0];     // [2,2048,1024]
  const float* W = (const float*)d_in[1];     // [1024,3072]
  const float* bias = (const float*)d_in[2];  // [3072]
  float* out = (float*)d_out;                 // [2,2048,1024]

  char* ws = (char*)d_ws;
  __hip_bfloat16* xb = (__hip_bfloat16*)ws;                    // 8,388,608 B
  __hip_bfloat16* Wt = (__hip_bfloat16*)(ws + 8388608);        // 6,291,456 B
  __hip_bfloat16* Qg = (__hip_bfloat16*)(ws + 14680064);       // 8,388,608 B
  __hip_bfloat16* Kg = (__hip_bfloat16*)(ws + 23068672);       // 8,388,608 B
  __hip_bfloat16* Vt = (__hip_bfloat16*)(ws + 31457280);       // 8,388,608 B

  k_prep<<<7168, 256, 0, stream>>>(x, W, xb, Wt);
  k_gemm<<<dim3(24, 32), 256, 0, stream>>>(xb, Wt, bias, Qg, Kg, Vt);
  k_attn<<<512, 256, 0, stream>>>(Qg, Kg, Vt, out);
}

// Round 10
// 176.589 us; speedup vs baseline: 1.2411x; 1.2411x over previous
//
#include <hip/hip_runtime.h>
#include <hip/hip_bf16.h>

typedef __attribute__((ext_vector_type(8))) short s8v;    // 8 bf16
typedef __attribute__((ext_vector_type(4))) short s4v;    // 4 bf16
typedef __attribute__((ext_vector_type(4))) float f4v;    // 4 fp32

__device__ __forceinline__ void g2lds16(const void* g, void* l) {
  __builtin_amdgcn_global_load_lds(
      (__attribute__((address_space(1))) void*)(g),
      (__attribute__((address_space(3))) void*)(l), 16, 0, 0);
}

__device__ __forceinline__ short f2bf(float f) {
  __hip_bfloat16 h = __float2bfloat16(f);
  return *reinterpret_cast<short*>(&h);
}

// ---------------- K0: fused x->bf16 cvt  +  W transpose->bf16 ----------------
__global__ void k_prep(const float* __restrict__ x, const float* __restrict__ W,
                       __hip_bfloat16* __restrict__ xb, __hip_bfloat16* __restrict__ Wt) {
  int bx = blockIdx.x;
  if (bx < 4096) {
    int i = (bx * 256 + threadIdx.x) * 4;
    float4 v = *(const float4*)(x + i);
    __hip_bfloat16 o[4] = {__float2bfloat16(v.x), __float2bfloat16(v.y),
                           __float2bfloat16(v.z), __float2bfloat16(v.w)};
    *(uint2*)(xb + i) = *(const uint2*)(o);
  } else {
    __shared__ float tile[32][33];
    int r = bx - 4096;            // 0..3071 = 32 x 96
    int rt = r / 96;              // over 1024/32
    int ct = r - rt * 96;         // over 3072/32
    int c0 = ct * 32, r0 = rt * 32;
    int tr = threadIdx.x >> 5, tc = threadIdx.x & 31;
#pragma unroll
    for (int i = 0; i < 32; i += 8)
      tile[tr + i][tc] = W[(size_t)(r0 + tr + i) * 3072 + c0 + tc];
    __syncthreads();
#pragma unroll
    for (int i = 0; i < 32; i += 8)
      Wt[(size_t)(c0 + tr + i) * 1024 + r0 + tc] = __float2bfloat16(tile[tc][tr + i]);
  }
}

// ---------------- K1: GEMM + fused QKV scatter epilogue ----------------
// (unchanged known-good: 128^2 tile, BK=32, 4 waves, 768 blocks, ~57.5us.
//  Attention scale 0.125*log2e folded into Q at the epilogue. No setprio
//  here: m190 measured setprio null/negative on lockstep GEMM.)
__global__ __launch_bounds__(256) void k_gemm(const __hip_bfloat16* __restrict__ A,
                                              const __hip_bfloat16* __restrict__ Bt,
                                              const float* __restrict__ bias,
                                              __hip_bfloat16* __restrict__ Q,
                                              __hip_bfloat16* __restrict__ K,
                                              __hip_bfloat16* __restrict__ Vt) {
  __shared__ __align__(16) __hip_bfloat16 As[2][128 * 32];
  __shared__ __align__(16) __hip_bfloat16 Bs[2][128 * 32];
  const int tid = threadIdx.x;
  const int lane = tid & 63, wave = tid >> 6;
  const int m0 = blockIdx.y * 128, n0 = blockIdx.x * 128;
  const int wm = (wave & 1) * 64, wn = (wave >> 1) * 64;
  const int lrow = lane & 15;
  const int quad = lane >> 4;

  f4v acc[4][4] = {};

  auto stage = [&](int k0, int kb) {
#pragma unroll
    for (int c = 0; c < 2; ++c) {
      int e = c * 2048 + tid * 8;             // element idx in 128x32 tile
      int row = e >> 5;
      int slot = (e & 31) >> 3;               // 0..3 (8-elem slots)
      int src = k0 + ((slot ^ ((row >> 1) & 3)) << 3);
      g2lds16(A + (size_t)(m0 + row) * 1024 + src, &As[kb][e]);
      g2lds16(Bt + (size_t)(n0 + row) * 1024 + src, &Bs[kb][e]);
    }
  };

  const int swz = (quad ^ ((lrow >> 1) & 3)) * 8;  // swizzled k-slot for frag reads

  stage(0, 0);
  for (int it = 0; it < 32; ++it) {
    __syncthreads();                    // drains stage(it) (issued one iter ago)
    if (it < 31) stage((it + 1) * 32, (it + 1) & 1);
    const __hip_bfloat16* Ab = As[it & 1];
    const __hip_bfloat16* Bb = Bs[it & 1];
    s8v af[4], bfr[4];
#pragma unroll
    for (int mi = 0; mi < 4; ++mi) af[mi] = *(const s8v*)(Ab + (wm + mi * 16 + lrow) * 32 + swz);
#pragma unroll
    for (int ni = 0; ni < 4; ++ni) bfr[ni] = *(const s8v*)(Bb + (wn + ni * 16 + lrow) * 32 + swz);
#pragma unroll
    for (int mi = 0; mi < 4; ++mi)
#pragma unroll
      for (int ni = 0; ni < 4; ++ni)
        acc[mi][ni] = __builtin_amdgcn_mfma_f32_16x16x32_bf16(af[mi], bfr[ni], acc[mi][ni], 0, 0, 0);
  }

  // epilogue: per-row destination decode, d-packed 8B stores for Q/K
  const int cw = n0 + wn;            // multiple of 64 -> c10 wave-uniform
  const int c10 = cw >> 10;          // 0..2
  const int d0 = (cw & 1023) >> 4;   // multiple of 4
  const int h = lrow;
  float bv[4];
#pragma unroll
  for (int ni = 0; ni < 4; ++ni) bv[ni] = bias[cw + ni * 16 + lrow];

#pragma unroll
  for (int mi = 0; mi < 4; ++mi) {
    int rbase = m0 + wm + mi * 16 + quad * 4;
#pragma unroll
    for (int reg = 0; reg < 4; ++reg) {
      int rr = rbase + reg;
      int u = 3 * rr + c10;
      int s = u >> 12;
      int b = (u >> 11) & 1;
      int t = u & 2047;
      if (s < 2) {
        __hip_bfloat16* dst = (s == 0) ? Q : K;
        // Q carries the attention scale: 0.125 * log2(e)
        const float qs = (s == 0) ? 0.18033688011112042f : 1.0f;
        s4v pk;
#pragma unroll
        for (int ni = 0; ni < 4; ++ni) pk[ni] = f2bf((acc[mi][ni][reg] + bv[ni]) * qs);
        *(s4v*)(dst + ((size_t)(b * 16 + h) * 2048 + t) * 64 + d0) = pk;
      } else {
#pragma unroll
        for (int ni = 0; ni < 4; ++ni)
          Vt[((size_t)(b * 16 + h) * 64 + d0 + ni) * 2048 + t] =
              __float2bfloat16(acc[mi][ni][reg] + bv[ni]);
      }
    }
  }
}

// ---------------- K2: causal flash attention ----------------
// Round-4 structure (best measured: 0.76us/wave-unit). Two isolated changes:
// (1) T5 s_setprio(1) around the S^T and PV MFMA clusters (m191: +4-7% on
//     attn-style kernels with independent blocks at different phases);
// (2) max/sum reductions rebalanced from depth-16 serial chains to depth-4
//     trees (nested fmaxf pairs also enable v_max3 fusion).
__global__ __launch_bounds__(256, 3) void k_attn(const __hip_bfloat16* __restrict__ Q,
                                                 const __hip_bfloat16* __restrict__ K,
                                                 const __hip_bfloat16* __restrict__ Vt,
                                                 float* __restrict__ out) {
  __shared__ __align__(16) char lds[2][16384];  // per buf: K tile 8KB | V tile 8KB

  const int tid = threadIdx.x;
  const int lane = tid & 63, w = tid >> 6;
  const int l = lane & 15, q = lane >> 4, lx = l & 7;

  const int bid = blockIdx.x;           // 1024 blocks
  const int xcd = bid & 7;
  const int idx = bid >> 3;             // 0..127
  const int bh = xcd + 8 * (idx & 3);   // 4 bh per XCD -> 2MB K+V in its L2
  const int qb = 31 - (idx >> 2);       // heavy blocks first; tiles 0..qb

  const char* Kb = (const char*)(K + (size_t)bh * 131072);
  const char* Vb = (const char*)(Vt + (size_t)bh * 131072);
  const __hip_bfloat16* Qp = Q + (size_t)bh * 131072 + (size_t)qb * 4096;

  // Q fragment (load once): B[n=t][k], t = qb*64 + w*16 + l
  s8v Qf[2];
#pragma unroll
  for (int kh = 0; kh < 2; ++kh)
    Qf[kh] = *(const s8v*)(Qp + (size_t)(w * 16 + l) * 64 + kh * 32 + q * 8);

  f4v O[4] = {};
  float m = -INFINITY, lsum = 0.f;
  const int tg = qb * 64 + w * 16 + l;          // this lane's global Q row

  auto stage = [&](int j, char* buf) {
#pragma unroll
    for (int c = 0; c < 4; ++c) {
      int chunk = w * 4 + c;            // 0..15
      int ls = chunk * 64 + lane;       // 16B-slot index
      if (chunk < 8) {                  // K tile: LDS[row][kb] = K[row][kb ^ (row&7)]
        int row = ls >> 3, kb = ls & 7;
        g2lds16(Kb + (size_t)j * 8192 + row * 128 + ((kb ^ (row & 7)) << 4),
                buf + ls * 16);
      } else {                          // V tile: LDS[d][kb] = V^T[d][kb ^ (d&7)]
        int ls2 = ls - 512;
        int d = ls2 >> 3, kb = ls2 & 7;
        g2lds16(Vb + (size_t)d * 4096 + (size_t)j * 128 + ((kb ^ (d & 7)) << 4),
                buf + 8192 + ls2 * 16);
      }
    }
  };

  stage(0, lds[0]);
  __syncthreads();

  for (int j = 0; j <= qb; ++j) {
    const char* Kl = lds[j & 1];
    const char* Vl = Kl + 8192;
    if (j < qb) stage(j + 1, lds[(j + 1) & 1]);

    // S^T: A = K rows (m = s_local), B = Q (n = t); S already log2-scaled
    f4v S[4];
    __builtin_amdgcn_s_setprio(1);
#pragma unroll
    for (int nt = 0; nt < 4; ++nt) {
      const char* rowp = Kl + (nt * 16 + l) * 128;
      s8v k0 = *(const s8v*)(rowp + ((q ^ lx) << 4));
      s8v k1 = *(const s8v*)(rowp + (((4 + q) ^ lx) << 4));
      f4v z = {0.f, 0.f, 0.f, 0.f};
      z = __builtin_amdgcn_mfma_f32_16x16x32_bf16(k0, Qf[0], z, 0, 0, 0);
      z = __builtin_amdgcn_mfma_f32_16x16x32_bf16(k1, Qf[1], z, 0, 0, 0);
      S[nt] = z;
    }
    __builtin_amdgcn_s_setprio(0);

    if (j == qb) {
#pragma unroll
      for (int nt = 0; nt < 4; ++nt)
#pragma unroll
        for (int r = 0; r < 4; ++r)
          if (j * 64 + nt * 16 + q * 4 + r > tg) S[nt][r] = -1e30f;
    }

    // depth-4 max tree (was depth-16 serial chain)
    float mnt[4];
#pragma unroll
    for (int nt = 0; nt < 4; ++nt)
      mnt[nt] = fmaxf(fmaxf(S[nt][0], S[nt][1]), fmaxf(S[nt][2], S[nt][3]));
    float mx = fmaxf(fmaxf(mnt[0], mnt[1]), fmaxf(mnt[2], mnt[3]));
    mx = fmaxf(mx, __shfl_xor(mx, 16));
    mx = fmaxf(mx, __shfl_xor(mx, 32));

    // T13 defer-max: rescale only when the max grew by > 8 (wave-uniform)
    if (!__all(mx - m <= 8.f)) {
      float mn = fmaxf(m, mx);
      float alpha = exp2f(m - mn);
      m = mn;
      lsum *= alpha;
#pragma unroll
      for (int dt = 0; dt < 4; ++dt) O[dt] *= alpha;
    }

    // exp pass with per-nt partial sums (depth-4 add tree, was depth-16)
    float rsp[4];
    s4v Pf[4];
#pragma unroll
    for (int nt = 0; nt < 4; ++nt) {
      float e0 = exp2f(S[nt][0] - m);
      float e1 = exp2f(S[nt][1] - m);
      float e2 = exp2f(S[nt][2] - m);
      float e3 = exp2f(S[nt][3] - m);
      Pf[nt][0] = f2bf(e0);
      Pf[nt][1] = f2bf(e1);
      Pf[nt][2] = f2bf(e2);
      Pf[nt][3] = f2bf(e3);
      rsp[nt] = (e0 + e1) + (e2 + e3);
    }
    float rs = (rsp[0] + rsp[1]) + (rsp[2] + rsp[3]);
    rs += __shfl_xor(rs, 16);
    rs += __shfl_xor(rs, 32);
    lsum += rs;

    // PV: A = V^T rows (m = d), B = P (n = t, k = s in C-layout regs)
    __builtin_amdgcn_s_setprio(1);
#pragma unroll
    for (int sc = 0; sc < 4; ++sc) {
      int so = ((sc * 2 + (q >> 1)) ^ lx) * 16 + (q & 1) * 8;
#pragma unroll
      for (int dt = 0; dt < 4; ++dt) {
        s4v vv = *(const s4v*)(Vl + (dt * 16 + l) * 128 + so);
        O[dt] = __builtin_amdgcn_mfma_f32_16x16x16bf16_1k(vv, Pf[sc], O[dt], 0, 0, 0);
      }
    }
    __builtin_amdgcn_s_setprio(0);
    __syncthreads();  // staging of j+1 drained; all waves done with buf (j&1)
  }

  // epilogue: lane holds row t = tg, cols d = dt*16 + q*4 + r  -> float4 stores
  float inv = 1.f / lsum;
  int b = bh >> 4, h = bh & 15;
  float* ob = out + ((size_t)b * 2048 + tg) * 1024 + h * 64;
#pragma unroll
  for (int dt = 0; dt < 4; ++dt) {
    f4v val = O[dt] * inv;
    *(f4v*)(ob + dt * 16 + q * 4) = val;
  }
}

extern "C" void kernel_launch(void* const* d_in, const int* in_sizes, int n_in,
                              void* d_out, int out_size, void* d_ws, size_t ws_size,
                              hipStream_t stream) {
  const float* x = (const float*)d_in[0];     // [2,2048,1024]
  const float* W = (const float*)d_in[1];     // [1024,3072]
  const float* bias = (const float*)d_in[2];  // [3072]
  float* out = (float*)d_out;                 // [2,2048,1024]

  char* ws = (char*)d_ws;
  __hip_bfloat16* xb = (__hip_bfloat16*)ws;                    // 8,388,608 B
  __hip_bfloat16* Wt = (__hip_bfloat16*)(ws + 8388608);        // 6,291,456 B
  __hip_bfloat16* Qg = (__hip_bfloat16*)(ws + 14680064);       // 8,388,608 B
  __hip_bfloat16* Kg = (__hip_bfloat16*)(ws + 23068672);       // 8,388,608 B
  __hip_bfloat16* Vt = (__hip_bfloat16*)(ws + 31457280);       // 8,388,608 B

  k_prep<<<7168, 256, 0, stream>>>(x, W, xb, Wt);
  k_gemm<<<dim3(24, 32), 256, 0, stream>>>(xb, Wt, bias, Qg, Kg, Vt);
  k_attn<<<1024, 256, 0, stream>>>(Qg, Kg, Vt, out);
}